// Round 3
// baseline (169.080 us; speedup 1.0000x reference)
//
#include <hip/hip_runtime.h>

typedef short bf16x8 __attribute__((ext_vector_type(8)));
typedef float f32x4 __attribute__((ext_vector_type(4)));

#define MFMA16(a, b, c) __builtin_amdgcn_mfma_f32_16x16x32_bf16(a, b, c, 0, 0, 0)

__device__ inline short f2bf(float f) {  // RNE, scalar epilogue use
  unsigned u = __builtin_bit_cast(unsigned, f);
  u += 0x7FFFu + ((u >> 16) & 1u);
  return (short)(u >> 16);
}
// pack two fp32 -> 2 bf16 in one dword; round-half-up (+0x8000) then v_perm byte-pack.
__device__ inline unsigned pack2(float lo, float hi) {
  unsigned a = __builtin_bit_cast(unsigned, lo) + 0x8000u;
  unsigned b = __builtin_bit_cast(unsigned, hi) + 0x8000u;
  return __builtin_amdgcn_perm(b, a, 0x07060302u);
}

// ---------------------------------------------------------------------------
// ws layout (bytes):
//   qs  = 0       : 256x1024 bf16 (524288)   Qs (pre-scaled by 1/32)
//   kwb = 524288  : 320x1024 bf16 (655360)   rows 0..209=K, 210..274=wk, 275..287=0, rest poison(harmless)
//   vt  = 1179648 : 1024x256 bf16 (524288)   V transposed [n][m]
//   Abf = 1703936 : 256x256  bf16 (131072)   A padded (cols>=210 zeroed for rows<224)
//   av  = 1835008 : 256x1024 bf16 (524288)   A@V
// total 2359296 bytes
// ---------------------------------------------------------------------------

// QKV: C[210x3072] = [Xmaj@Wq*scale | Xmin@Wk | Xmin@Wv], bf16 out, fp32 X converted inline.
// Blocks 0..191: 4 m-tiles x 48 n-tiles of 64x64, K=2048, BK=64. XCD swizzle: the 4
// m-tiles sharing a weight tile land on one XCD (L2 reuse). Blocks 192..193: wk convert.
__global__ __launch_bounds__(256) void k_qkv(const float* __restrict__ xmaj,
                                             const float* __restrict__ xmin,
                                             const float* __restrict__ Wq,
                                             const float* __restrict__ Wk,
                                             const float* __restrict__ Wv,
                                             const float* __restrict__ wkin,
                                             short* __restrict__ qs,
                                             short* __restrict__ kwb,
                                             short* __restrict__ vt) {
  int b = blockIdx.x;
  int t = threadIdx.x;
  if (b >= 192) {  // tail blocks: convert wk (65x1024) into kwb rows 210..274, zero 275..287
    int idx = (b - 192) * 256 + t;
    const float4* src = (const float4*)wkin;
    uint2* dst = (uint2*)(kwb + 210 * 1024);
    for (int i = idx; i < 16640; i += 512) {
      float4 v = src[i];
      dst[i] = make_uint2(pack2(v.x, v.y), pack2(v.z, v.w));
    }
    uint4 z = make_uint4(0, 0, 0, 0);
    uint4* zd = (uint4*)(kwb + 275 * 1024);
    for (int i = idx; i < 1664; i += 512) zd[i] = z;
    return;
  }

  __shared__ short As[64][72];
  __shared__ short Bs[64][72];
  int x = b & 7, s = b >> 3;
  int ntile = x * 6 + (s >> 2);
  int mtile = s & 3;
  int nn0 = ntile * 64;
  int mat = nn0 >> 10;
  int ncol0 = nn0 & 1023;
  int m0 = mtile * 64;
  const float* Xa = (mat == 0) ? xmaj : xmin;
  const float* W = (mat == 0) ? Wq : (mat == 1 ? Wk : Wv);
  int lane = t & 63, w = t >> 6;
  int wm = w >> 1, wn = w & 1;
  int l15 = lane & 15, l4 = lane >> 4;
  f32x4 acc[2][2] = {};
  int arow = t >> 3, ac8 = t & 7;
  int bkp = t >> 4, bc4 = t & 15;
  int g1 = m0 + arow; if (g1 > 209) g1 = 209;        // clamp: avoid OOB fp32 X reads
  int g2 = m0 + arow + 32; if (g2 > 209) g2 = 209;
  const float* xr1 = Xa + (size_t)g1 * 2048;
  const float* xr2 = Xa + (size_t)g2 * 2048;

  for (int k0 = 0; k0 < 2048; k0 += 64) {
    __syncthreads();
    // A stage: fp32 -> bf16 inline, 2 rows x 8 elems per thread
    {
      float4 f0 = *(const float4*)(xr1 + k0 + ac8 * 8);
      float4 f1 = *(const float4*)(xr1 + k0 + ac8 * 8 + 4);
      *(uint4*)&As[arow][ac8 * 8] =
          make_uint4(pack2(f0.x, f0.y), pack2(f0.z, f0.w), pack2(f1.x, f1.y), pack2(f1.z, f1.w));
      float4 g0 = *(const float4*)(xr2 + k0 + ac8 * 8);
      float4 g1v = *(const float4*)(xr2 + k0 + ac8 * 8 + 4);
      *(uint4*)&As[arow + 32][ac8 * 8] =
          make_uint4(pack2(g0.x, g0.y), pack2(g0.z, g0.w), pack2(g1v.x, g1v.y), pack2(g1v.z, g1v.w));
    }
    // B stage with transpose: W[k][n] fp32 -> Bs[n][k] bf16, paired-k b32 writes
    for (int h = 0; h < 2; ++h) {
      int kp = bkp + h * 16;
      const float* gp = W + (size_t)(k0 + 2 * kp) * 1024 + ncol0 + bc4 * 4;
      float4 w0 = *(const float4*)gp;
      float4 w1 = *(const float4*)(gp + 1024);
      int nl = bc4 * 4;
      *(unsigned*)&Bs[nl + 0][2 * kp] = pack2(w0.x, w1.x);
      *(unsigned*)&Bs[nl + 1][2 * kp] = pack2(w0.y, w1.y);
      *(unsigned*)&Bs[nl + 2][2 * kp] = pack2(w0.z, w1.z);
      *(unsigned*)&Bs[nl + 3][2 * kp] = pack2(w0.w, w1.w);
    }
    __syncthreads();
    for (int kk = 0; kk < 2; ++kk) {
      int ko = kk * 32 + l4 * 8;
      bf16x8 a0 = *(const bf16x8*)&As[wm * 32 + l15][ko];
      bf16x8 a1 = *(const bf16x8*)&As[wm * 32 + 16 + l15][ko];
      bf16x8 b0 = *(const bf16x8*)&Bs[wn * 32 + l15][ko];
      bf16x8 b1 = *(const bf16x8*)&Bs[wn * 32 + 16 + l15][ko];
      acc[0][0] = MFMA16(a0, b0, acc[0][0]);
      acc[0][1] = MFMA16(a0, b1, acc[0][1]);
      acc[1][0] = MFMA16(a1, b0, acc[1][0]);
      acc[1][1] = MFMA16(a1, b1, acc[1][1]);
    }
  }

  if (mat < 2) {
    float scale = (mat == 0) ? 0.03125f : 1.0f;
    short* dst = (mat == 0) ? qs : kwb;
    for (int mi = 0; mi < 2; ++mi)
      for (int ni = 0; ni < 2; ++ni) {
        int r0 = m0 + wm * 32 + mi * 16 + l4 * 4;
        int c = ncol0 + wn * 32 + ni * 16 + l15;
        for (int j = 0; j < 4; ++j) {
          int r = r0 + j;
          if (r < 210) dst[r * 1024 + c] = f2bf(acc[mi][ni][j] * scale);
        }
      }
  } else {
    // V: transpose tile via LDS, store Vt[n][m] coalesced
    __syncthreads();
    for (int mi = 0; mi < 2; ++mi)
      for (int ni = 0; ni < 2; ++ni) {
        int nl = wn * 32 + ni * 16 + l15;
        int ml0 = wm * 32 + mi * 16 + l4 * 4;
        for (int j = 0; j < 4; ++j) As[nl][ml0 + j] = f2bf(acc[mi][ni][j]);
      }
    __syncthreads();
    for (int h = 0; h < 2; ++h) {
      int idx = t + h * 256;
      int nl = idx >> 3, c8 = idx & 7;
      int mg0 = m0 + c8 * 8;
      short* dstp = vt + (ncol0 + nl) * 256 + mg0;
      if (mg0 + 8 <= 210) {
        *(uint4*)dstp = *(const uint4*)&As[nl][c8 * 8];
      } else {
        for (int e = 0; e < 8; ++e)
          if (mg0 + e < 210) dstp[e] = As[nl][c8 * 8 + e];
      }
    }
  }
}

// Fused S' + softmax. Grid 7 blocks x 32 rows. Each block: S'[32][288] = Qs-rows @ [K;wk]^T
// (waves own 80-col strips; cols>=288 read kwb poison -> finite garbage, discarded),
// then table-gather + row softmax entirely in LDS.
#define SST 292  // Ssh row stride (floats); 292%32==4 breaks LDS bank aliasing
__global__ __launch_bounds__(256) void k_attn(const short* __restrict__ qs,
                                              const short* __restrict__ kwb,
                                              const int* __restrict__ table,
                                              short* __restrict__ Abf,
                                              float* __restrict__ outA) {
  __shared__ short As[32][72];
  __shared__ short Bs[320][72];          // 46080 B; aliased by Ssh after K-loop
  float* Ssh = (float*)&Bs[0][0];        // 32 x SST floats = 37376 B <= 46080
  int m0 = blockIdx.x * 32;
  int t = threadIdx.x, lane = t & 63, w = t >> 6;
  int l15 = lane & 15, l4 = lane >> 4;
  f32x4 acc[2][5] = {};
  int arow = t >> 3, ac8 = t & 7;

  for (int k0 = 0; k0 < 1024; k0 += 64) {
    __syncthreads();
    *(uint4*)&As[arow][ac8 * 8] = *(const uint4*)(qs + (m0 + arow) * 1024 + k0 + ac8 * 8);
    for (int j = 0; j < 10; ++j) {
      int s = t + j * 256;
      int r = s >> 3, c8 = s & 7;
      *(uint4*)&Bs[r][c8 * 8] = *(const uint4*)(kwb + r * 1024 + k0 + c8 * 8);
    }
    __syncthreads();
    for (int kk = 0; kk < 2; ++kk) {
      int ko = kk * 32 + l4 * 8;
      bf16x8 a0 = *(const bf16x8*)&As[l15][ko];
      bf16x8 a1 = *(const bf16x8*)&As[16 + l15][ko];
      for (int ni = 0; ni < 5; ++ni) {
        bf16x8 bb = *(const bf16x8*)&Bs[w * 80 + ni * 16 + l15][ko];
        acc[0][ni] = MFMA16(a0, bb, acc[0][ni]);
        acc[1][ni] = MFMA16(a1, bb, acc[1][ni]);
      }
    }
  }
  __syncthreads();  // all Bs reads done before aliasing as Ssh
  for (int mi = 0; mi < 2; ++mi)
    for (int ni = 0; ni < 5; ++ni) {
      int col = w * 80 + ni * 16 + l15;
      if (col < 288) {
        int r0 = mi * 16 + l4 * 4;
        for (int jj = 0; jj < 4; ++jj) Ssh[(r0 + jj) * SST + col] = acc[mi][ni][jj];
      }
    }
  __syncthreads();

  int r = t >> 3, c = t & 7;  // 8 threads per row; lanes of a row share a width-8 shfl group
  int row = m0 + r;
  float* Sr = Ssh + r * SST;
  if (row < 210) {
    const int* tr = table + row * 210;
    float mx = -1e30f;
    for (int j = c; j < 210; j += 8) {
      float lg = Sr[j] + Sr[210 + tr[j]];  // gather targets 210..274 never overwritten
      Sr[j] = lg;
      mx = fmaxf(mx, lg);
    }
    for (int o = 4; o; o >>= 1) mx = fmaxf(mx, __shfl_xor(mx, o, 8));
    float sum = 0.0f;
    for (int j = c; j < 210; j += 8) {
      float e = __expf(Sr[j] - mx);
      Sr[j] = e;
      sum += e;
    }
    for (int o = 4; o; o >>= 1) sum += __shfl_xor(sum, o, 8);
    float inv = 1.0f / sum;
    for (int j = c; j < 210; j += 8) {
      float a = Sr[j] * inv;
      outA[row * 210 + j] = a;
      Abf[row * 256 + j] = f2bf(a);
    }
    for (int j = 210 + c; j < 256; j += 8) Abf[row * 256 + j] = 0;
  } else {
    for (int j = c; j < 256; j += 8) Abf[row * 256 + j] = 0;
  }
}

// AV = A(pad bf16) @ V : uses Vt[n][k]. Blocks 64x64, grid(16,4), K=256.
__global__ __launch_bounds__(256) void k_av(const short* __restrict__ Abf,
                                            const short* __restrict__ vt,
                                            short* __restrict__ av) {
  __shared__ short As[64][72];
  __shared__ short Bs[64][72];
  int n0 = blockIdx.x * 64, m0 = blockIdx.y * 64;
  int t = threadIdx.x, lane = t & 63, w = t >> 6;
  int wm = w >> 1, wn = w & 1;
  int l15 = lane & 15, l4 = lane >> 4;
  f32x4 acc[2][2] = {};
  int arow = t >> 3, ac8 = t & 7;
  for (int k0 = 0; k0 < 256; k0 += 64) {
    __syncthreads();
    *(uint4*)&As[arow][ac8 * 8] = *(const uint4*)(Abf + (m0 + arow) * 256 + k0 + ac8 * 8);
    *(uint4*)&As[arow + 32][ac8 * 8] = *(const uint4*)(Abf + (m0 + arow + 32) * 256 + k0 + ac8 * 8);
    *(uint4*)&Bs[arow][ac8 * 8] = *(const uint4*)(vt + (n0 + arow) * 256 + k0 + ac8 * 8);
    *(uint4*)&Bs[arow + 32][ac8 * 8] = *(const uint4*)(vt + (n0 + arow + 32) * 256 + k0 + ac8 * 8);
    __syncthreads();
    for (int kk = 0; kk < 2; ++kk) {
      int ko = kk * 32 + l4 * 8;
      bf16x8 a0 = *(const bf16x8*)&As[wm * 32 + l15][ko];
      bf16x8 a1 = *(const bf16x8*)&As[wm * 32 + 16 + l15][ko];
      bf16x8 b0 = *(const bf16x8*)&Bs[wn * 32 + l15][ko];
      bf16x8 b1 = *(const bf16x8*)&Bs[wn * 32 + 16 + l15][ko];
      acc[0][0] = MFMA16(a0, b0, acc[0][0]);
      acc[0][1] = MFMA16(a0, b1, acc[0][1]);
      acc[1][0] = MFMA16(a1, b0, acc[1][0]);
      acc[1][1] = MFMA16(a1, b1, acc[1][1]);
    }
  }
  for (int mi = 0; mi < 2; ++mi)
    for (int ni = 0; ni < 2; ++ni) {
      int r0 = m0 + wm * 32 + mi * 16 + l4 * 4;
      int c = n0 + wn * 32 + ni * 16 + l15;
      for (int j = 0; j < 4; ++j) {
        int r = r0 + j;
        if (r < 210) av[r * 1024 + c] = f2bf(acc[mi][ni][j]);
      }
    }
}

// Y = AV @ Wo : AV bf16 [m][k] k=1024, Wo fp32 transposed+packed in staging. grid(16,4). fp32 out.
__global__ __launch_bounds__(256) void k_y(const short* __restrict__ av,
                                           const float* __restrict__ Wo,
                                           float* __restrict__ outY) {
  __shared__ short As[64][72];
  __shared__ short Bs[64][72];
  int n0 = blockIdx.x * 64, m0 = blockIdx.y * 64;
  int t = threadIdx.x, lane = t & 63, w = t >> 6;
  int wm = w >> 1, wn = w & 1;
  int l15 = lane & 15, l4 = lane >> 4;
  f32x4 acc[2][2] = {};
  int arow = t >> 3, ac8 = t & 7;
  int bkp = t >> 4, bc4 = t & 15;
  for (int k0 = 0; k0 < 1024; k0 += 64) {
    __syncthreads();
    *(uint4*)&As[arow][ac8 * 8] = *(const uint4*)(av + (m0 + arow) * 1024 + k0 + ac8 * 8);
    *(uint4*)&As[arow + 32][ac8 * 8] = *(const uint4*)(av + (m0 + arow + 32) * 1024 + k0 + ac8 * 8);
    for (int h = 0; h < 2; ++h) {
      int kp = bkp + h * 16;
      const float* gp = Wo + (size_t)(k0 + 2 * kp) * 1024 + n0 + bc4 * 4;
      float4 w0 = *(const float4*)gp;
      float4 w1 = *(const float4*)(gp + 1024);
      int nl = bc4 * 4;
      *(unsigned*)&Bs[nl + 0][2 * kp] = pack2(w0.x, w1.x);
      *(unsigned*)&Bs[nl + 1][2 * kp] = pack2(w0.y, w1.y);
      *(unsigned*)&Bs[nl + 2][2 * kp] = pack2(w0.z, w1.z);
      *(unsigned*)&Bs[nl + 3][2 * kp] = pack2(w0.w, w1.w);
    }
    __syncthreads();
    for (int kk = 0; kk < 2; ++kk) {
      int ko = kk * 32 + l4 * 8;
      bf16x8 a0 = *(const bf16x8*)&As[wm * 32 + l15][ko];
      bf16x8 a1 = *(const bf16x8*)&As[wm * 32 + 16 + l15][ko];
      bf16x8 b0 = *(const bf16x8*)&Bs[wn * 32 + l15][ko];
      bf16x8 b1 = *(const bf16x8*)&Bs[wn * 32 + 16 + l15][ko];
      acc[0][0] = MFMA16(a0, b0, acc[0][0]);
      acc[0][1] = MFMA16(a0, b1, acc[0][1]);
      acc[1][0] = MFMA16(a1, b0, acc[1][0]);
      acc[1][1] = MFMA16(a1, b1, acc[1][1]);
    }
  }
  for (int mi = 0; mi < 2; ++mi)
    for (int ni = 0; ni < 2; ++ni) {
      int r0 = m0 + wm * 32 + mi * 16 + l4 * 4;
      int c = n0 + wn * 32 + ni * 16 + l15;
      for (int j = 0; j < 4; ++j) {
        int r = r0 + j;
        if (r < 210) outY[r * 1024 + c] = acc[mi][ni][j];
      }
    }
}

extern "C" void kernel_launch(void* const* d_in, const int* in_sizes, int n_in,
                              void* d_out, int out_size, void* d_ws, size_t ws_size,
                              hipStream_t stream) {
  const float* Xmaj = (const float*)d_in[0];
  const float* Xmin = (const float*)d_in[1];
  const float* Wq = (const float*)d_in[2];
  const float* Wk = (const float*)d_in[3];
  const float* Wv = (const float*)d_in[4];
  const float* Wo = (const float*)d_in[5];
  const float* wk = (const float*)d_in[6];
  const int* table = (const int*)d_in[7];

  char* ws = (char*)d_ws;
  short* qs = (short*)(ws + 0);
  short* kwb = (short*)(ws + 524288);
  short* vt = (short*)(ws + 1179648);
  short* Abf = (short*)(ws + 1703936);
  short* av = (short*)(ws + 1835008);

  float* outY = (float*)d_out;           // 210*1024 fp32
  float* outA = (float*)d_out + 215040;  // 210*210 fp32

  k_qkv<<<194, 256, 0, stream>>>(Xmaj, Xmin, Wq, Wk, Wv, wk, qs, kwb, vt);
  k_attn<<<7, 256, 0, stream>>>(qs, kwb, table, Abf, outA);
  k_av<<<dim3(16, 4), 256, 0, stream>>>(Abf, vt, av);
  k_y<<<dim3(16, 4), 256, 0, stream>>>(av, Wo, outY);
}